// Round 6
// baseline (244.936 us; speedup 1.0000x reference)
//
#include <hip/hip_runtime.h>
#include <stdint.h>

// ---------------------------------------------------------------------------
// GCN 2-layer. R16: XCD-L2-resident gathers via channel slicing. zw stored as
// 4 slices of 32 ch (64B rows, 3.2MB/slice <= 4MB XCD L2). aggp blocks pick
// slice = (bid%8)>>1 so (round-robin block->XCD) each XCD gathers only from
// its own L2-resident slice: L3-latency gathers -> L2-latency. Wave = 4 nodes
// x 16 lanes; ids broadcast per-group via ds_bpermute; per-channel accum order
// unchanged vs R15. gemm writes zw sliced; z1b / z_out stay linear.
// 5 dispatches: k0 -> k5(gemm1(+)fill) -> aggp<false> -> gemm2k(dinv-fold) ->
// aggp<true>.
// ---------------------------------------------------------------------------

#define CAP 96

typedef __attribute__((ext_vector_type(8))) short short8;
typedef __attribute__((ext_vector_type(4))) float f32x4;

__device__ __forceinline__ uint16_t bf16rne(float f) {
    uint32_t u = __float_as_uint(f);
    uint32_t r = (u + 0x7fffu + ((u >> 16) & 1u)) >> 16;
    return (uint16_t)r;
}
__device__ __forceinline__ float bf_lo(uint32_t v) { return __uint_as_float(v << 16); }
__device__ __forceinline__ float bf_hi(uint32_t v) { return __uint_as_float(v & 0xffff0000u); }

// ---- K0 (512 thr): zero cursor(N+1) + 4 slice pad rows | prep_w | zero g_out
__global__ __launch_bounds__(512) void k0(int* __restrict__ cursor, int nbC, int N,
                                          const float* __restrict__ W1,
                                          const float* __restrict__ W2,
                                          uint16_t* __restrict__ Wf1,
                                          uint16_t* __restrict__ Wf2,
                                          float* __restrict__ g_out, int nbZ,
                                          uint32_t* __restrict__ zw, int SL) {
    int bid = blockIdx.x, t = threadIdx.x;
    if (bid < nbC) {
        int i = bid * 512 + t;
        if (i <= N) cursor[i] = 0;
        if (bid == 0 && t < 64)  // pad row (node N) of each slice = 0
            zw[(size_t)(t >> 4) * SL + (size_t)N * 16 + (t & 15)] = 0u;
    } else if (bid < nbC + 8) {
        int tid = (bid - nbC) * 512 + t;        // 0..4095
        const float* W = (tid & 2048) ? W2 : W1;
        uint16_t* O = (tid & 2048) ? Wf2 : Wf1;
        int q16 = tid & 2047;
        int lane = q16 & 63, n0ks = q16 >> 6;
        int n0 = n0ks >> 2, ks = n0ks & 3;
        int m = lane & 15, quad = lane >> 4;
        int nn = n0 * 16 + m;
        int kkb = ks * 32 + quad * 8;
        uint16_t v[8];
#pragma unroll
        for (int j = 0; j < 8; ++j) v[j] = bf16rne(W[(kkb + j) * 128 + nn]);
        *(short8*)&O[q16 * 8] = *(short8*)v;
    } else {
        int idx = (bid - nbC - 8) * 512 + t;    // nbZ blocks x 512 float4s
        ((float4*)g_out)[idx] = make_float4(0.f, 0.f, 0.f, 0.f);
    }
}

// ---- gemm body (8 waves, M=128 tile); optional dinv-fold; sliced Y if ySL ----
__device__ __forceinline__ void gemm_body(const float* Xf, const uint16_t* Xb,
                                          const uint16_t* __restrict__ Wf,
                                          uint16_t* __restrict__ Y, int nrows,
                                          const int* __restrict__ cnt,  // nullptr -> no fold
                                          uint16_t* Wl, int bid, int t, int ySL) {
    int lane = t & 63, w = t >> 6;
    int row0 = bid * 128;
    for (int c = t; c < 2048; c += 512)
        *(short8*)&Wl[c * 8] = *(const short8*)&Wf[c * 8];
    int m = lane & 15, quad = lane >> 4;
    int arow = row0 + w * 16 + m;
    bool rowok = arow < nrows;
    short8 a[4];
    short8 zer = {0, 0, 0, 0, 0, 0, 0, 0};
    if (Xb) {
        const uint16_t* aptr = Xb + (size_t)arow * 128 + quad * 8;
#pragma unroll
        for (int ks = 0; ks < 4; ++ks)
            a[ks] = rowok ? *(const short8*)(aptr + ks * 32) : zer;
    } else {
        const float* ap = Xf + (size_t)arow * 128 + quad * 8;
#pragma unroll
        for (int ks = 0; ks < 4; ++ks) {
            if (rowok) {
                float4 u0 = *(const float4*)(ap + ks * 32);
                float4 u1 = *(const float4*)(ap + ks * 32 + 4);
                uint32_t q[4];
                q[0] = (uint32_t)bf16rne(u0.x) | ((uint32_t)bf16rne(u0.y) << 16);
                q[1] = (uint32_t)bf16rne(u0.z) | ((uint32_t)bf16rne(u0.w) << 16);
                q[2] = (uint32_t)bf16rne(u1.x) | ((uint32_t)bf16rne(u1.y) << 16);
                q[3] = (uint32_t)bf16rne(u1.z) | ((uint32_t)bf16rne(u1.w) << 16);
                a[ks] = *(short8*)q;
            } else a[ks] = zer;
        }
    }
    __syncthreads();

    f32x4 acc[8];
#pragma unroll
    for (int i = 0; i < 8; ++i) acc[i] = (f32x4){0.f, 0.f, 0.f, 0.f};
#pragma unroll
    for (int ks = 0; ks < 4; ++ks)
#pragma unroll
        for (int n0 = 0; n0 < 8; ++n0) {
            short8 b = *(short8*)&Wl[((n0 * 4 + ks) * 64 + lane) * 8];
            acc[n0] = __builtin_amdgcn_mfma_f32_16x16x32_bf16(a[ks], b, acc[n0], 0, 0, 0);
        }
    __syncthreads();  // all 8 waves done reading Wl; reuse as epilogue buffer

    float dsc[4] = {1.f, 1.f, 1.f, 1.f};
    if (cnt) {
#pragma unroll
        for (int r = 0; r < 4; ++r) {
            int gr = row0 + w * 16 + quad * 4 + r;
            int d = (gr < nrows) ? cnt[gr] : 0;
            dsc[r] = rsqrtf((float)(d + 1));
        }
    }

    uint16_t* Ep = Wl;  // [128][136] view, wave-private 16-row bands
#pragma unroll
    for (int n0 = 0; n0 < 8; ++n0)
#pragma unroll
        for (int r = 0; r < 4; ++r)
            Ep[(w * 16 + quad * 4 + r) * 136 + n0 * 16 + m] = bf16rne(acc[n0][r] * dsc[r]);
    for (int r16 = 0; r16 < 16; ++r16) {
        int row = row0 + w * 16 + r16;
        if (row < nrows) {
            uint32_t v = *(uint32_t*)&Ep[(w * 16 + r16) * 136 + lane * 2];
            if (ySL)  // slice (lane>>4) holds ch-pair dword (lane&15) of row
                ((uint32_t*)Y)[(size_t)(lane >> 4) * ySL + (size_t)row * 16 + (lane & 15)] = v;
            else
                ((uint32_t*)Y)[(size_t)row * 64 + lane] = v;
        }
    }
}

// ---- fill body (512 thr): 4 edges/thread; bucket write (u16) + deg count ----
__device__ __forceinline__ void fill_body(const int* __restrict__ src, const int* __restrict__ dst,
                                          int* __restrict__ cursor, uint16_t* __restrict__ col,
                                          int E, int fb, int t) {
    int base = fb * 2048 + t;
    int d[4], s[4], p[4];
#pragma unroll
    for (int k = 0; k < 4; ++k) {
        int e = base + k * 512;
        d[k] = (e < E) ? dst[e] : -1;
        s[k] = (e < E) ? src[e] : 0;
    }
#pragma unroll
    for (int k = 0; k < 4; ++k) if (d[k] >= 0) p[k] = atomicAdd(&cursor[d[k]], 1);
#pragma unroll
    for (int k = 0; k < 4; ++k)
        if (d[k] >= 0 && p[k] < CAP) col[(size_t)d[k] * CAP + p[k]] = (uint16_t)s[k];
}

// ---- K5: gemm1 (+) fill interleaved ----
__global__ __launch_bounds__(512, 8) void k5(const float* __restrict__ X,
                                             const uint16_t* __restrict__ Wf,
                                             uint16_t* __restrict__ Y, int nrows, int gemmGrid,
                                             const int* __restrict__ src, const int* __restrict__ dst,
                                             int* __restrict__ cursor, uint16_t* __restrict__ col,
                                             int E, int fillGrid, int SL) {
    __shared__ uint16_t Wl[17408];
    int bid = blockIdx.x, t = threadIdx.x;
    int mn = min(gemmGrid, fillGrid), mn2 = 2 * mn;
    int role, idx;
    if (bid < mn2) { role = bid & 1; idx = bid >> 1; }
    else { role = (gemmGrid > fillGrid) ? 0 : 1; idx = bid - mn2 + mn; }
    if (role == 0) gemm_body(X, nullptr, Wf, Y, nrows, nullptr, Wl, idx, t, SL);
    else fill_body(src, dst, cursor, col, E, idx, t);
}

// ---- gemm standalone (layer 2): M=128, 512 thr, dinv fold, sliced Y ----
__global__ __launch_bounds__(512, 8) void gemm2k(const uint16_t* __restrict__ Xb,
                                                 const uint16_t* __restrict__ Wf,
                                                 uint16_t* __restrict__ Y, int nrows,
                                                 const int* __restrict__ cnt, int SL) {
    __shared__ uint16_t Wl[17408];
    gemm_body(nullptr, Xb, Wf, Y, nrows, cnt, Wl, blockIdx.x, threadIdx.x, SL);
}

// ---- agg + fused pool, channel-sliced: block -> slice s=(bid%8)>>1 (XCD
//      affinity); wave = 4 nodes x 16 lanes; each lane: 1 dword (2ch) of its
//      node's slice row. ids via ds_bpermute from per-group bucket regs.
//      Pad-to-8 via zero row (id=n). PS=true: zw pre-scaled by dinv ----
template <bool PS>
__global__ __launch_bounds__(256) void aggp(const uint32_t* __restrict__ zw,
                                            const int* __restrict__ cnt,
                                            const uint16_t* __restrict__ col,
                                            const float* __restrict__ bias,
                                            const float* __restrict__ alpha,
                                            const int* __restrict__ batch,
                                            float* __restrict__ gout, int col_off,
                                            uint32_t* __restrict__ z1b,
                                            float* __restrict__ zoutf,
                                            int mode, int n, int SL, int NB) {
    __shared__ int gsh[16];
    __shared__ float red[4][32];
    int bid = blockIdx.x;
    int s = (bid & 7) >> 1;                 // slice (2 XCDs per slice)
    int j = ((bid >> 3) << 1) | (bid & 1);  // node-quad-block index within slice
    if (j >= NB) return;
    int t = threadIdx.x;
    int wv = t >> 6, lane = t & 63;
    int g = lane >> 4, i = lane & 15;
    int node = j * 16 + wv * 4 + g;
    bool valid = node < n;
    int nd = valid ? node : n;              // row n = zero pad row, cnt[n]=0
    int ncl = valid ? node : (n - 1);       // clamped for bucket reads only
    const uint32_t* zs = zw + (size_t)s * SL;
    int deg = cnt[nd];
    float di = rsqrtf((float)(deg + 1));
    uint32_t sv = zs[(uint32_t)nd * 16 + i];
    float sw = PS ? 1.f : di;
    float ax = sw * bf_lo(sv), ay = sw * bf_hi(sv);  // self (x di again at end)
    float bx = 0.f, by = 0.f;
    int len = min(deg, CAP);
    int len8 = (len + 7) & ~7;
    // wave-uniform loop bound = max len8 over the 4 groups
    int m1 = max(len8, __shfl_xor(len8, 16));
    int mx = __builtin_amdgcn_readfirstlane(max(m1, __shfl_xor(m1, 32)));
    int permbase = (lane & 48) << 2;        // byte addr of own group's lane 0
    const uint32_t* cbu = (const uint32_t*)col;

    for (int c0 = 0; c0 < mx; c0 += 32) {
        // own node's ids for this 32-edge chunk: lane i holds edges 2i,2i+1
        uint32_t cc = cbu[(uint32_t)ncl * (CAP / 2) + (c0 >> 1) + i];
        int top = min(mx - c0, 32);
        for (int e = 0; e < top; e += 8) {
            uint32_t q0 = (uint32_t)__builtin_amdgcn_ds_bpermute(permbase + (((e + 0) >> 1) << 2), (int)cc);
            uint32_t q1 = (uint32_t)__builtin_amdgcn_ds_bpermute(permbase + (((e + 2) >> 1) << 2), (int)cc);
            uint32_t q2 = (uint32_t)__builtin_amdgcn_ds_bpermute(permbase + (((e + 4) >> 1) << 2), (int)cc);
            uint32_t q3 = (uint32_t)__builtin_amdgcn_ds_bpermute(permbase + (((e + 6) >> 1) << 2), (int)cc);
            int jj = c0 + e;
            int s0 = (jj + 0 < len) ? (int)(q0 & 0xffffu) : n;
            int s1 = (jj + 1 < len) ? (int)(q0 >> 16)     : n;
            int s2 = (jj + 2 < len) ? (int)(q1 & 0xffffu) : n;
            int s3 = (jj + 3 < len) ? (int)(q1 >> 16)     : n;
            int s4 = (jj + 4 < len) ? (int)(q2 & 0xffffu) : n;
            int s5 = (jj + 5 < len) ? (int)(q2 >> 16)     : n;
            int s6 = (jj + 6 < len) ? (int)(q3 & 0xffffu) : n;
            int s7 = (jj + 7 < len) ? (int)(q3 >> 16)     : n;
            uint32_t v0 = zs[(uint32_t)s0 * 16 + i];
            uint32_t v1 = zs[(uint32_t)s1 * 16 + i];
            uint32_t v2 = zs[(uint32_t)s2 * 16 + i];
            uint32_t v3 = zs[(uint32_t)s3 * 16 + i];
            uint32_t v4 = zs[(uint32_t)s4 * 16 + i];
            uint32_t v5 = zs[(uint32_t)s5 * 16 + i];
            uint32_t v6 = zs[(uint32_t)s6 * 16 + i];
            uint32_t v7 = zs[(uint32_t)s7 * 16 + i];
            float w0 = PS ? 1.f : rsqrtf((float)(cnt[s0] + 1));
            float w1 = PS ? 1.f : rsqrtf((float)(cnt[s1] + 1));
            float w2 = PS ? 1.f : rsqrtf((float)(cnt[s2] + 1));
            float w3 = PS ? 1.f : rsqrtf((float)(cnt[s3] + 1));
            float w4 = PS ? 1.f : rsqrtf((float)(cnt[s4] + 1));
            float w5 = PS ? 1.f : rsqrtf((float)(cnt[s5] + 1));
            float w6 = PS ? 1.f : rsqrtf((float)(cnt[s6] + 1));
            float w7 = PS ? 1.f : rsqrtf((float)(cnt[s7] + 1));
            ax += w0 * bf_lo(v0); ay += w0 * bf_hi(v0);
            bx += w1 * bf_lo(v1); by += w1 * bf_hi(v1);
            ax += w2 * bf_lo(v2); ay += w2 * bf_hi(v2);
            bx += w3 * bf_lo(v3); by += w3 * bf_hi(v3);
            ax += w4 * bf_lo(v4); ay += w4 * bf_hi(v4);
            bx += w5 * bf_lo(v5); by += w5 * bf_hi(v5);
            ax += w6 * bf_lo(v6); ay += w6 * bf_hi(v6);
            bx += w7 * bf_lo(v7); by += w7 * bf_hi(v7);
        }
    }
    ax += bx; ay += by;
    float2 bb = ((const float2*)bias)[s * 16 + i];
    float2 aa = ((const float2*)alpha)[s * 16 + i];
    float zx = di * ax + bb.x;
    float zy = di * ay + bb.y;
    zx = zx > 0.f ? zx : aa.x * zx;
    zy = zy > 0.f ? zy : aa.y * zy;

    if (valid) {
        if (mode == 0) {
            uint32_t pk = (uint32_t)bf16rne(zx) | ((uint32_t)bf16rne(zy) << 16);
            z1b[(size_t)node * 64 + s * 16 + i] = pk;
        } else {
            ((float2*)zoutf)[(size_t)node * 64 + s * 16 + i] = make_float2(zx, zy);
        }
    }

    // ---- pool: block-uniform fast path (16 nodes same graph) ----
    int gr = valid ? batch[nd] : -1;
    if (i == 0) gsh[wv * 4 + g] = gr;
    __syncthreads();
    int g0 = gsh[0];
    bool uni = true;
#pragma unroll
    for (int q = 1; q < 16; ++q) uni &= (gsh[q] == g0);
    float cx = valid ? zx : 0.f, cy = valid ? zy : 0.f;
    if (uni) {
        float r1x = cx + __shfl_xor(cx, 16), r1y = cy + __shfl_xor(cy, 16);
        float r2x = r1x + __shfl_xor(r1x, 32), r2y = r1y + __shfl_xor(r1y, 32);
        if (lane < 16) { red[wv][2 * i] = r2x; red[wv][2 * i + 1] = r2y; }
        __syncthreads();
        if (wv == 0 && lane < 16) {
            float sx = red[0][2 * i] + red[1][2 * i] + red[2][2 * i] + red[3][2 * i];
            float sy = red[0][2 * i + 1] + red[1][2 * i + 1] + red[2][2 * i + 1] + red[3][2 * i + 1];
            float* base = &gout[(size_t)g0 * 256 + col_off + s * 32 + 2 * i];
            atomicAdd(&base[0], sx);
            atomicAdd(&base[1], sy);
        }
    } else {
        if (valid) {
            float* base = &gout[(size_t)gr * 256 + col_off + s * 32 + 2 * i];
            atomicAdd(&base[0], cx);
            atomicAdd(&base[1], cy);
        }
    }
}

extern "C" void kernel_launch(void* const* d_in, const int* in_sizes, int n_in,
                              void* d_out, int out_size, void* d_ws, size_t ws_size,
                              hipStream_t stream) {
    const float* x     = (const float*)d_in[0];
    const int*   eidx  = (const int*)d_in[1];
    const int*   batch = (const int*)d_in[2];
    const float* W1    = (const float*)d_in[3];
    const float* b1    = (const float*)d_in[4];
    const float* W2    = (const float*)d_in[5];
    const float* b2    = (const float*)d_in[6];
    const float* alpha = (const float*)d_in[7];

    const int N = in_sizes[2];
    const int E = in_sizes[1] / 2;
    const int G = (out_size - N * 128) / 256;

    const int* src = eidx;
    const int* dst = eidx + E;

    char* ws = (char*)d_ws;
    size_t off = 0;
    auto alloc = [&](size_t bytes) { void* q = ws + off; off = (off + bytes + 255) & ~(size_t)255; return q; };
    int*      cursor = (int*)alloc((size_t)(N + 1) * 4);
    uint16_t* col    = (uint16_t*)alloc((size_t)N * CAP * 2);
    uint32_t* zw     = (uint32_t*)alloc((size_t)(N + 1) * 128 * 2);  // 4 slices x (N+1) x 64B
    uint32_t* z1b    = (uint32_t*)alloc((size_t)N * 128 * 2);
    uint16_t* Wf1    = (uint16_t*)alloc(128 * 128 * 2);
    uint16_t* Wf2    = (uint16_t*)alloc(128 * 128 * 2);

    float* z_out = (float*)d_out;
    float* g_out = (float*)d_out + (size_t)N * 128;

    const int SL = (N + 1) * 16;               // slice stride in dwords
    int nbC      = (N + 512) / 512;            // cursor zero (N+1 entries)
    int nbZ      = (G * 256 / 4 + 511) / 512;  // g_out zero (float4)
    int fillGrid = (E + 2047) / 2048;          // 4 edges/thread x 512
    int gemmGrid = (N + 127) / 128;            // M=128 tiles x 512 thr
    int NB       = (N + 15) / 16;              // node-quad blocks per slice
    int NBpad    = (NB + 1) & ~1;
    int aggGrid  = NBpad * 4;

    k0<<<nbC + 8 + nbZ, 512, 0, stream>>>(cursor, nbC, N, W1, W2, Wf1, Wf2, g_out, nbZ, zw, SL);
    k5<<<gemmGrid + fillGrid, 512, 0, stream>>>(x, Wf1, (uint16_t*)zw, N, gemmGrid,
                                                src, dst, cursor, col, E, fillGrid, SL);
    aggp<false><<<aggGrid, 256, 0, stream>>>(zw, cursor, col, b1, alpha, batch,
                                             g_out, 0, z1b, nullptr, 0, N, SL, NB);
    gemm2k<<<gemmGrid, 512, 0, stream>>>((const uint16_t*)z1b, Wf2, (uint16_t*)zw, N, cursor, SL);
    aggp<true><<<aggGrid, 256, 0, stream>>>(zw, cursor, col, b2, alpha, batch,
                                            g_out, 128, nullptr, z_out, 1, N, SL, NB);
}